// Round 3
// baseline (223.041 us; speedup 1.0000x reference)
//
#include <hip/hip_runtime.h>
#include <math.h>

#define IMG_H 512
#define IMG_W 512
#define NIMG 32
#define HALO 17
#define W_T 256         // output cols per block
#define H_T 64          // output rows per block
#define RB 8            // input rows per batch
#define SW 292          // staged row width (290 used: x0-17 .. x0+272)
#define T5W 288         // win5 row width (286 used)
#define NBATCH 13       // ceil((H_T+34)/RB) = 13 (rows 98..103 padded -inf)

// Fully fused dark-channel loss: cmax -> horizontal win35 (5+7 in LDS) ->
// vertical win35 (5+7 register pipeline) -> |.| -> mean. No d_ws usage.
__global__ __launch_bounds__(256) void dc_fused(const float* __restrict__ img,
                                                float* __restrict__ out) {
    __shared__ float rowbuf[RB][SW];
    __shared__ float tmp5[RB][T5W];
    __shared__ float wsum[4];
    const int b = blockIdx.x;             // n*16 + yt*2 + xt
    const int xt = b & 1;
    const int yt = (b >> 1) & 7;
    const int n = b >> 4;
    const int x0 = xt * W_T;
    const int y0 = yt * H_T;
    const int tid = (int)threadIdx.x;
    const float* base = img + (size_t)n * 3 * IMG_H * IMG_W;

    float A[H_T];
    float r0 = 0.f, r1 = 0.f, r2 = 0.f, r3 = 0.f, r4 = 0.f;
    float s = 0.f;

    #pragma unroll
    for (int bt = 0; bt < NBATCH; ++bt) {
        // ---- stage RB rows of cmax = 1 - min3(img) into LDS, -inf halo ----
        #pragma unroll
        for (int j = 0; j < RB; ++j) {
            const int m = bt * RB + j;
            const int gy = y0 - HALO + m;
            const bool rowok = (m < H_T + 2 * HALO) && (gy >= 0) && (gy < IMG_H);
            #pragma unroll
            for (int ii = 0; ii < 2; ++ii) {
                const int i = tid + ii * 256;
                if (i < W_T + 2 * HALO) {
                    const int gx = x0 - HALO + i;
                    float v = -INFINITY;
                    if (rowok && gx >= 0 && gx < IMG_W) {
                        const size_t o = (size_t)gy * IMG_W + gx;
                        float a0 = base[o];
                        float a1 = base[o + IMG_H * IMG_W];
                        float a2 = base[o + 2 * IMG_H * IMG_W];
                        v = 1.0f - fminf(a0, fminf(a1, a2));
                    }
                    rowbuf[j][i] = v;
                }
            }
        }
        __syncthreads();
        // ---- horizontal win5: tmp5[j][i] = max(rowbuf[j][i..i+4]) ----
        #pragma unroll
        for (int j = 0; j < RB; ++j) {
            #pragma unroll
            for (int ii = 0; ii < 2; ++ii) {
                const int i = tid + ii * 256;
                if (i < W_T + 30) {
                    float m5 = rowbuf[j][i];
                    m5 = fmaxf(m5, rowbuf[j][i + 1]);
                    m5 = fmaxf(m5, rowbuf[j][i + 2]);
                    m5 = fmaxf(m5, rowbuf[j][i + 3]);
                    m5 = fmaxf(m5, rowbuf[j][i + 4]);
                    tmp5[j][i] = m5;
                }
            }
        }
        __syncthreads();
        // ---- horizontal win35 (regs) + vertical 5+7 pipeline ----
        #pragma unroll
        for (int j = 0; j < RB; ++j) {
            const int m = bt * RB + j;
            float h = tmp5[j][tid];
            #pragma unroll
            for (int k = 1; k < 7; ++k) h = fmaxf(h, tmp5[j][tid + 5 * k]);
            r0 = r1; r1 = r2; r2 = r3; r3 = r4; r4 = h;
            if (m >= 4) {
                const int mg = m - 4;    // compile-time after unroll
                const float g = fmaxf(fmaxf(fmaxf(r0, r1), fmaxf(r2, r3)), r4);
                #pragma unroll
                for (int k = 0; k < 7; ++k) {
                    const int i = mg - 5 * k;
                    if (i >= 0 && i < H_T) {
                        if (i == mg) A[i] = g;          // first touch (k==0)
                        else A[i] = fmaxf(A[i], g);
                    }
                }
                if (mg >= 30 && mg <= H_T + 29) s += fabsf(A[mg - 30]);
            }
        }
        // next batch: stage rewrites rowbuf (win5 reads done before barrier B);
        // win5 rewrites tmp5 only after next barrier A. Two barriers/batch suffice.
    }

    // ---- block reduction + one atomic ----
    #pragma unroll
    for (int off = 32; off > 0; off >>= 1) s += __shfl_down(s, off);
    const int lane = tid & 63, wv = tid >> 6;
    if (lane == 0) wsum[wv] = s;
    __syncthreads();
    if (tid == 0) {
        float t = wsum[0] + wsum[1] + wsum[2] + wsum[3];
        atomicAdd(out, t * (1.0f / ((float)NIMG * IMG_H * IMG_W)));
    }
}

extern "C" void kernel_launch(void* const* d_in, const int* in_sizes, int n_in,
                              void* d_out, int out_size, void* d_ws, size_t ws_size,
                              hipStream_t stream) {
    const float* img = (const float*)d_in[0];
    float* out = (float*)d_out;
    (void)d_ws; (void)ws_size;

    hipMemsetAsync(d_out, 0, sizeof(float), stream);
    dc_fused<<<NIMG * (IMG_H / H_T) * (IMG_W / W_T), 256, 0, stream>>>(img, out);
}

// Round 4
// 179.090 us; speedup vs baseline: 1.2454x; 1.2454x over previous
//
#include <hip/hip_runtime.h>
#include <math.h>

#define IMG_H 512
#define IMG_W 512
#define NIMG 32
#define W_T 256         // output cols per block
#define H_T 32          // output rows per block
#define RB 11           // staged input rows per batch (6*11 = 66 = H_T + 34 exactly)
#define NBATCH 6
#define SW 296          // staged floats/row: gx in [x0-20, x0+276)
#define SQ 74           // staged float4/row
#define TW 288          // win5 floats/row (centers c=0..285 used)
#define TQ 72           // win5 float4/row

// Fused dark-channel loss. cmax = 1 - min3(img); 35-tap max = win5 then 7-tap
// stride-5 (both axes). Horizontal in LDS (vectorized), vertical in a static
// register pipeline with A[32] accumulators. One atomicAdd per block.
__global__ __launch_bounds__(256) void dc_fused(const float* __restrict__ img,
                                                float* __restrict__ out) {
    __shared__ float rowbuf[RB][SW];
    __shared__ float tmp5[RB][TW];
    __shared__ float wsum[4];
    const int b = blockIdx.x;              // n*32 + yt*2 + xt
    const int xt = b & 1;
    const int yt = (b >> 1) & 15;
    const int n = b >> 5;
    const int x0 = xt * W_T;
    const int y0 = yt * H_T;
    const int tid = (int)threadIdx.x;
    const float4* img4 = (const float4*)img + (size_t)n * 196608;  // n*3*H*W/4

    float A[H_T];
    float r0 = 0.f, r1 = 0.f, r2 = 0.f, r3 = 0.f, r4 = 0.f;
    float s = 0.f;

    #pragma unroll
    for (int bt = 0; bt < NBATCH; ++bt) {
        // ---- stage RB rows of cmax into LDS: unconditional clamped float4 loads ----
        #pragma unroll
        for (int ii = 0; ii < 4; ++ii) {
            const int p = tid + ii * 256;
            if (p < RB * SQ) {
                const int j = p / SQ, q = p - j * SQ;
                const int gy = y0 - 17 + bt * RB + j;
                const int gyc = min(max(gy, 0), IMG_H - 1);
                const int gx0 = x0 - 20 + (q << 2);          // always multiple of 4
                const int gxc = min(max(gx0, 0), IMG_W - 4); // float4 fully in or out
                const bool ok = (gy == gyc) && (gx0 == gxc);
                const float4* p0 = img4 + ((size_t)gyc << 7) + (gxc >> 2);
                const float4 a = p0[0];
                const float4 c1 = p0[65536];    // + H*W/4
                const float4 c2 = p0[131072];   // + 2*H*W/4
                float4 f;
                f.x = ok ? 1.0f - fminf(a.x, fminf(c1.x, c2.x)) : -INFINITY;
                f.y = ok ? 1.0f - fminf(a.y, fminf(c1.y, c2.y)) : -INFINITY;
                f.z = ok ? 1.0f - fminf(a.z, fminf(c1.z, c2.z)) : -INFINITY;
                f.w = ok ? 1.0f - fminf(a.w, fminf(c1.w, c2.w)) : -INFINITY;
                *(float4*)&rowbuf[j][q << 2] = f;
            }
        }
        __syncthreads();
        // ---- horizontal win5, 4 slots/thread from 3 aligned b128 reads ----
        // tmp5[j][c] = max(rowbuf[j][c+3 .. c+7])  (win5 centered at x0-15+c)
        #pragma unroll
        for (int ii = 0; ii < 4; ++ii) {
            const int p = tid + ii * 256;
            if (p < RB * TQ) {
                const int j = p / TQ, q = p - j * TQ;
                const float* rp = &rowbuf[j][q << 2];
                const float4 a  = *(const float4*)(rp);
                const float4 bq = *(const float4*)(rp + 4);
                const float4 cq = *(const float4*)(rp + 8);
                const float sb1 = fmaxf(bq.y, fmaxf(bq.z, bq.w));
                const float m4b = fmaxf(bq.x, sb1);
                const float sb2 = fmaxf(bq.z, bq.w);
                const float pc2 = fmaxf(cq.x, cq.y);
                float4 t;
                t.x = fmaxf(a.w, m4b);                 // rowbuf[4q+3 .. 4q+7]
                t.y = fmaxf(m4b, cq.x);                // [4q+4 .. 4q+8]
                t.z = fmaxf(sb1, pc2);                 // [4q+5 .. 4q+9]
                t.w = fmaxf(sb2, fmaxf(pc2, cq.z));    // [4q+6 .. 4q+10]
                *(float4*)&tmp5[j][q << 2] = t;
            }
        }
        __syncthreads();
        // ---- horizontal win35 gather + vertical 5+7 register pipeline ----
        #pragma unroll
        for (int j = 0; j < RB; ++j) {
            const int m = bt * RB + j;                 // compile-time
            float h = tmp5[j][tid];
            #pragma unroll
            for (int k = 1; k < 7; ++k) h = fmaxf(h, tmp5[j][tid + 5 * k]);
            r0 = r1; r1 = r2; r2 = r3; r3 = r4; r4 = h;
            if (m >= 4) {
                const int mg = m - 4;                  // compile-time
                const float g = fmaxf(fmaxf(fmaxf(r0, r1), fmaxf(r2, r3)), r4);
                #pragma unroll
                for (int k = 0; k < 7; ++k) {
                    const int i = mg - 5 * k;
                    if (i >= 0 && i < H_T) {
                        if (i == mg) A[i] = g;         // first touch (k==0)
                        else A[i] = fmaxf(A[i], g);
                    }
                }
                if (mg >= 30) s += fabsf(A[mg - 30]);  // output row y0+mg-30 done
            }
        }
        // stage(bt+1) writes rowbuf only (phase3 reads tmp5) and the barrier
        // after stage orders win5(bt) reads vs stage(bt+1) writes -> 2 barriers/batch.
    }

    // ---- block reduction + one atomic ----
    #pragma unroll
    for (int off = 32; off > 0; off >>= 1) s += __shfl_down(s, off);
    const int lane = tid & 63, wv = tid >> 6;
    if (lane == 0) wsum[wv] = s;
    __syncthreads();
    if (tid == 0) {
        float t = wsum[0] + wsum[1] + wsum[2] + wsum[3];
        atomicAdd(out, t * (1.0f / ((float)NIMG * IMG_H * IMG_W)));
    }
}

extern "C" void kernel_launch(void* const* d_in, const int* in_sizes, int n_in,
                              void* d_out, int out_size, void* d_ws, size_t ws_size,
                              hipStream_t stream) {
    const float* img = (const float*)d_in[0];
    float* out = (float*)d_out;
    (void)d_ws; (void)ws_size;

    hipMemsetAsync(d_out, 0, sizeof(float), stream);
    dc_fused<<<NIMG * (IMG_H / H_T) * (IMG_W / W_T), 256, 0, stream>>>(img, out);
}

// Round 5
// 168.922 us; speedup vs baseline: 1.3204x; 1.0602x over previous
//
#include <hip/hip_runtime.h>
#include <math.h>

#define IMG_H 512
#define IMG_W 512
#define NIMG 32
#define AR 4            // rows per block, pass A
#define SW 552          // rowbuf floats/row: rb[i] = cmax(x = i - 20), i in [0,552)
#define SQ 138          // float4/row staged
#define TW 544          // tmp5 floats/row: tmp5[i] = win5 centered at x = i - 15
#define TQ 136          // float4/row of win5
#define YC 32           // output rows per block, pass B

// ---------------- Pass A: cmax + horizontal win35 -> rowmax (ws) ----------------
__global__ __launch_bounds__(256) void dc_rowmax(const float* __restrict__ img,
                                                 float* __restrict__ rowmax) {
    __shared__ float rowbuf[AR][SW];
    __shared__ float tmp5[AR][TW];
    const int b = blockIdx.x;             // n*128 + ytile
    const int n = b >> 7;
    const int y0 = (b & 127) * AR;
    const int tid = (int)threadIdx.x;
    const float4* img4 = (const float4*)img + (size_t)n * 196608;   // n*3*H*W/4

    // stage: unconditional clamped float4 loads, cndmask halo to -inf
    #pragma unroll
    for (int ii = 0; ii < 3; ++ii) {
        const int p = tid + ii * 256;
        if (p < AR * SQ) {
            const int r = p / SQ, q = p - r * SQ;
            const int gx0 = (q << 2) - 20;
            const int gxc = min(max(gx0, 0), IMG_W - 4);   // float4 fully in or out
            const bool ok = (gx0 == gxc);
            const float4* p0 = img4 + (((size_t)(y0 + r)) << 7) + (gxc >> 2);
            const float4 a  = p0[0];
            const float4 c1 = p0[65536];
            const float4 c2 = p0[131072];
            float4 f;
            f.x = ok ? 1.0f - fminf(a.x, fminf(c1.x, c2.x)) : -INFINITY;
            f.y = ok ? 1.0f - fminf(a.y, fminf(c1.y, c2.y)) : -INFINITY;
            f.z = ok ? 1.0f - fminf(a.z, fminf(c1.z, c2.z)) : -INFINITY;
            f.w = ok ? 1.0f - fminf(a.w, fminf(c1.w, c2.w)) : -INFINITY;
            *(float4*)&rowbuf[r][q << 2] = f;
        }
    }
    __syncthreads();
    // win5: tmp5[r][i] = max(rowbuf[r][i+3 .. i+7]), 4 slots from 3 b128 reads
    #pragma unroll
    for (int ii = 0; ii < 3; ++ii) {
        const int p = tid + ii * 256;
        if (p < AR * TQ) {
            const int r = p / TQ, q = p - r * TQ;
            const float* rp = &rowbuf[r][q << 2];
            const float4 a  = *(const float4*)(rp);
            const float4 bq = *(const float4*)(rp + 4);
            const float4 cq = *(const float4*)(rp + 8);
            const float sb1 = fmaxf(bq.y, fmaxf(bq.z, bq.w));
            const float m4b = fmaxf(bq.x, sb1);
            const float sb2 = fmaxf(bq.z, bq.w);
            const float pc2 = fmaxf(cq.x, cq.y);
            float4 t;
            t.x = fmaxf(a.w, m4b);
            t.y = fmaxf(m4b, cq.x);
            t.z = fmaxf(sb1, pc2);
            t.w = fmaxf(sb2, fmaxf(pc2, cq.z));
            *(float4*)&tmp5[r][q << 2] = t;
        }
    }
    __syncthreads();
    // win35: out[x] = max_k tmp5[x + 5k], k=0..6 (centers x-15+5k)
    float* orow = rowmax + ((size_t)n * IMG_H + y0) * IMG_W;
    #pragma unroll
    for (int ii = 0; ii < 8; ++ii) {
        const int idx = tid + ii * 256;          // 0 .. 2047
        const int r = idx >> 9, x = idx & 511;
        float m = tmp5[r][x];
        #pragma unroll
        for (int k = 1; k < 7; ++k) m = fmaxf(m, tmp5[r][x + 5 * k]);
        orow[(size_t)r * IMG_W + x] = m;
    }
}

// ------- Pass B: vertical win35 (5+7 register pipeline) + mean reduction -------
__global__ __launch_bounds__(256) void dc_colmax(const float* __restrict__ rowmax,
                                                 float* __restrict__ out) {
    __shared__ float wsum[4];
    const int b = blockIdx.x;             // n*32 + yt*2 + xt
    const int xt = b & 1;
    const int yt = (b >> 1) & 15;
    const int n = b >> 5;
    const int x = xt * 256 + (int)threadIdx.x;
    const int y0 = yt * YC;
    const float* col = rowmax + (size_t)n * IMG_H * IMG_W + x;

    float A[YC];
    float r0 = 0.f, r1 = 0.f, r2 = 0.f, r3 = 0.f, r4 = 0.f;
    float s = 0.f;
    #pragma unroll
    for (int m = 0; m < YC + 34; ++m) {
        const int gy = y0 - 17 + m;
        const int gyc = min(max(gy, 0), IMG_H - 1);
        const float v = col[(size_t)gyc << 9];          // unconditional load
        const float vv = (gy == gyc) ? v : -INFINITY;   // cndmask, no branch
        r0 = r1; r1 = r2; r2 = r3; r3 = r4; r4 = vv;
        if (m >= 4) {
            const int mg = m - 4;                        // compile-time after unroll
            const float g = fmaxf(fmaxf(fmaxf(r0, r1), fmaxf(r2, r3)), r4);
            #pragma unroll
            for (int k = 0; k < 7; ++k) {
                const int i = mg - 5 * k;
                if (i >= 0 && i < YC) {
                    if (i == mg) A[i] = g;               // first touch (k==0)
                    else A[i] = fmaxf(A[i], g);
                }
            }
            if (mg >= 30) s += fabsf(A[mg - 30]);
        }
    }
    #pragma unroll
    for (int off = 32; off > 0; off >>= 1) s += __shfl_down(s, off);
    const int lane = (int)threadIdx.x & 63, wv = (int)threadIdx.x >> 6;
    if (lane == 0) wsum[wv] = s;
    __syncthreads();
    if (threadIdx.x == 0) {
        float t = wsum[0] + wsum[1] + wsum[2] + wsum[3];
        atomicAdd(out, t * (1.0f / ((float)NIMG * IMG_H * IMG_W)));
    }
}

extern "C" void kernel_launch(void* const* d_in, const int* in_sizes, int n_in,
                              void* d_out, int out_size, void* d_ws, size_t ws_size,
                              hipStream_t stream) {
    const float* img = (const float*)d_in[0];
    float* out = (float*)d_out;
    float* rowmax = (float*)d_ws;     // 33.5 MB scratch (poisoned by harness anyway)

    hipMemsetAsync(d_out, 0, sizeof(float), stream);
    dc_rowmax<<<NIMG * (IMG_H / AR), 256, 0, stream>>>(img, rowmax);
    dc_colmax<<<NIMG * (IMG_H / YC) * 2, 256, 0, stream>>>(rowmax, out);
}